// Round 1
// 122.766 us; speedup vs baseline: 1.0127x; 1.0127x over previous
//
#include <hip/hip_runtime.h>
#include <math.h>

#define BLOCK 256
#define SPB (BLOCK / 4)   // 64 samples per block; 4 lanes cooperate per sample
// Session rules: (R4) no runtime-indexed register arrays; (R5) no fine-grained
// scalar guards around register-resident straight-line code; (R7) dynamic chunk
// loops with wave-uniform scalar bounds + LDS t-table; (R9) exact-count pairing
// + i=1 shift; (R10) prefetch double-buffer; (R11) merged adjacent edge pairs.
// R12 (this rev): LDS record handoff. Phase 1 (gather + f64 edge chain) writes
// per-sample records (x, log2 x, im) to LDS instead of holding 9-wide register
// arrays + 63 ds_bpermute broadcasts -> whole-kernel VGPR allocation no longer
// taxed by the preamble; phase-2 pair loops read records via 4-lane broadcast
// (stride 10 coprime with 32 -> conflict-free across groups) and compute a
// per-pair wave-max (== old max(Mw[j1],Mw[j2]) by monotonicity of ceil/4).
// Edge 8 merged with the denominator into a FIXED 16-chunk loop: extra chunks
// for edge 8 are masked to exact +0.0 (R11 argument), den order unchanged.
// All per-edge sums bit-identical to R11.

struct F4a4 { float a, b, c, d; };   // 16B load at 4B alignment -> global_load_dwordx4

__device__ __forceinline__ float exp2_fast(float x) {
#if __has_builtin(__builtin_amdgcn_exp2f)
    return __builtin_amdgcn_exp2f(x);   // bare v_exp_f32
#else
    return __expf(x * 0.69314718055994531f);
#endif
}

// Inline f64 exp, rel err ~7e-15. Proven R5-R10 (absmax identical to libm).
__device__ __forceinline__ double exp_f64_fast(double x) {
    const double L2E = 1.4426950408889634074;
    const double LN2 = 0.69314718055994530942;
    double n = rint(x * L2E);
    double r = fma(x, L2E, -n);
    double w = r * LN2;
    double p = 2.08767569878680989792e-9;             // 1/12!
    p = fma(p, w, 2.50521083854417187751e-8);
    p = fma(p, w, 2.75573192239858906526e-7);
    p = fma(p, w, 2.75573192239858925110e-6);
    p = fma(p, w, 2.48015873015873015873e-5);
    p = fma(p, w, 1.98412698412698412698e-4);
    p = fma(p, w, 1.38888888888888888889e-3);
    p = fma(p, w, 8.33333333333333333333e-3);
    p = fma(p, w, 4.16666666666666666667e-2);
    p = fma(p, w, 1.66666666666666666667e-1);
    p = fma(p, w, 0.5);
    p = fma(p, w, 1.0);
    p = fma(p, w, 1.0);
    const double sc = __longlong_as_double((long long)(1023 + (int)n) << 52);
    return p * sc;
}

__global__ __launch_bounds__(BLOCK) void lbd_kernel(
    const int* __restrict__ uid_in, const int* __restrict__ iid_in,
    const float* __restrict__ uf,  const float* __restrict__ vf,
    const float* __restrict__ ubt, const float* __restrict__ ibt,
    const float* __restrict__ uae, const float* __restrict__ ube,
    const float* __restrict__ iae, const float* __restrict__ ibe,
    const float* __restrict__ gbp, float* __restrict__ out, int B)
{
    // Sample-independent t-grid tables: built once per block.
    // s_num padded to 76: prefetch reads up to index 72 (m=14, sub=3); pad
    // entries are (t=1, lt=0) -> finite math, masked to exact 0 if consumed.
    // s_den padded to 72: pad entries (0,0) are prefetch-only, never consumed.
    __shared__ float2 s_num[76];       // (t_i, log2 t_i)
    __shared__ float2 s_den[72];       // (log2 t_i, log2(1-t_i)); [63] -> -inf => exact 0
    // Per-sample edge records (phase-1 -> phase-2 handoff). Row padded to 10
    // floats: pair reads 8B-aligned, stride 10 coprime with 32 banks.
    __shared__ float  s_x [SPB][10];
    __shared__ float  s_lx[SPB][10];
    __shared__ int    s_im[SPB][10];

    const int tid = threadIdx.x;
    {
        const double STEP0 = 1.0 / 63.0;
        if (tid < 76) {
            const float tf = (tid >= 63) ? 1.0f : (float)((double)tid * STEP0); // exact np linspace f32
            s_num[tid] = make_float2(tf, __log2f(tf));      // tid>=63 -> (1, 0)
        }
        if (tid < 72) {
            float l1 = 0.f, l2 = 0.f;
            if (tid < 64) {
                const float tf = (tid >= 63) ? 1.0f : (float)((double)tid * STEP0);
                l1 = __log2f(tf);
                l2 = __log2f(1.0f - tf);                    // tid==63 -> -inf
            }
            s_den[tid] = make_float2(l1, l2);
        }
    }
    __syncthreads();

    const int sub = tid & 3;                          // lane within 4-lane sample group
    const int g   = tid >> 2;                         // sample group within block
    const int s0  = blockIdx.x * SPB + g;
    const bool valid = (s0 < B);
    const int s = valid ? s0 : (B - 1);               // clamp: keep lanes live for shuffles

    const int u = uid_in[s];
    const int v = iid_in[s];

    // ---- feature gather: 4 x dwordx4 per table; lane covers 16c+4*sub..+3 -----
    const float* pu = uf + (long long)u * 65;
    const float* pv = vf + (long long)v * 65;
    float dotp = 0.f, sup = 0.f, svp = 0.f;
#pragma unroll
    for (int c = 0; c < 4; ++c) {
        const F4a4 a = *(const F4a4*)(pu + c * 16 + sub * 4);
        const F4a4 b = *(const F4a4*)(pv + c * 16 + sub * 4);
        dotp += a.a * b.a + a.b * b.b + a.c * b.c + a.d * b.d;
        sup  += a.a * a.a + a.b * a.b + a.c * a.c + a.d * a.d;
        svp  += b.a * b.a + b.b * b.b + b.c * b.c + b.d * b.d;
    }
#pragma unroll
    for (int d = 1; d < 4; d <<= 1) {                 // butterfly within 4-group
        dotp += __shfl_xor(dotp, d, 64);
        sup  += __shfl_xor(sup,  d, 64);
        svp  += __shfl_xor(svp,  d, 64);
    }

    // ---- embedding gather dedup: 1 load/lane + shuffles (smooth path) ---------
    float emb;
    {
        const float* ep = (sub == 0) ? (uae + u)
                        : (sub == 1) ? (iae + v)
                        : (sub == 2) ? (ube + u)
                        :              (ibe + v);
        emb = *ep;
    }
    const float ua_ = __shfl(emb, 0, 4);
    const float ia_ = __shfl(emb, 1, 4);
    const float ub_ = __shfl(emb, 2, 4);
    const float ib_ = __shfl(emb, 3, 4);

    // ---- alpha / beta (smooth; 4 lanes redundantly) ---------------------------
    const float gb = gbp[0];
    const float len_prod = sqrtf(sup) * sqrtf(svp);
    const float EPS = 1e-6f;
    const float HI  = (float)(1.0 - 1e-6);
    float mu = 0.5f + (0.5f * dotp) / fmaxf(len_prod, EPS);
    mu = fminf(fmaxf(mu, EPS), HI);
    const float ups = fmaxf(fabsf(dotp), EPS);
    const float al0 = fmaxf(0.01f, mu * ups);
    const float be0 = fmaxf(0.01f, ups - al0);
    const float alpha = fmaxf(0.01f, ((gb + al0) + ua_) + ia_);
    const float beta  = fmaxf(0.01f, ((gb + be0) + ub_) + ib_);
    const float am1 = alpha - 1.0f;                   // > 0 (gb = 2.0)
    const float bm1 = beta  - 1.0f;                   // > 0

    // ---- bin-edge chain in f64 (mask-critical; slop budget ~1e-11 rel) --------
    // Lane sub owns contiguous bins lb..lb+2 (lane3: bin 9 only).
    const double STEP = 1.0 / 63.0;
    const int lb = 3 * sub;
    double e0, e1 = 0.0, e2 = 0.0;
    {
        const long long ur = (long long)u * 10, vr = (long long)v * 10;
        const int i1 = (lb + 1 <= 9) ? lb + 1 : 9;    // clamp to stay in-bounds
        const int i2 = (lb + 2 <= 9) ? lb + 2 : 9;
        e0 = exp_f64_fast((double)ubt[ur + lb] + (double)ibt[vr + lb]);
        const double t1 = exp_f64_fast((double)ubt[ur + i1] + (double)ibt[vr + i1]);
        const double t2 = exp_f64_fast((double)ubt[ur + i2] + (double)ibt[vr + i2]);
        if (lb + 1 <= 9) e1 = t1;                     // lane3 contributes only bin 9
        if (lb + 2 <= 9) e2 = t2;
    }
    const double c0 = e0, c1 = c0 + e1, c2 = c1 + e2; // local cumsum (3 bins)
    double p = c2;                                    // local total
#pragma unroll
    for (int d = 1; d < 4; d <<= 1) {                 // inclusive scan of totals
        const double t = __shfl_up(p, d, 4);
        if (sub >= d) p += t;
    }
    const double ssum = __shfl(p, 3, 4);              // grand total (10 bins)
    const double rsum = 1.0 / ssum;                   // 1 IEEE div; <=2ulp slop ok
    const double ex   = p - c2;                       // exclusive prefix
    // own edges -> LDS record (global edge index lb+r, valid if <= 8)
    const double cg0 = ex + c0, cg1 = ex + c1, cg2 = ex + c2;
#pragma unroll
    for (int r = 0; r < 3; ++r) {
        const double cgr = (r == 0) ? cg0 : (r == 1) ? cg1 : cg2;
        if (lb + r <= 8) {
            const double x = cgr * rsum;              // f64 mul by reciprocal
            int k = (int)(x * 63.0);
            k = (k > 62) ? 62 : k;
            const int dec = ((double)k * STEP > x) ? 1 : 0;
            const int inc = ((k < 62) && ((double)(k + 1) * STEP <= x)) ? 1 : 0;
            const float xf = (float)x;
            s_im[g][lb + r] = k + inc - dec;          // exact im, branch-free
            s_x [g][lb + r] = xf;
            s_lx[g][lb + r] = __log2f(xf);
        }
    }
    __syncthreads();   // record visibility (cheap: one barrier, 4 waves/block)

    // ---- hoisted first pair: identical addresses for ALL loops ----------------
    const float2 P0 = s_num[sub + 1];                 // i of trip 0
    const float2 P1 = s_num[sub + 5];                 // i of trip 1

    float acc[9];
    float accD = 0.f;

    // ---- merged edge-pair loops: records from LDS, per-pair wave-max trips ----
    // max(ceil(iA/4), ceil(iB/4)) == ceil(max(iA,iB)/4): M identical to R11's
    // max(Mw[j1], Mw[j2]). Accumulation pattern (even chunks -> a?0, odd -> a?1,
    // ascending m) unchanged; extra trips for the smaller edge add exact +0.0.
#define PAIR_LOOP(j1, j2)                                                          \
    {                                                                              \
        const float xA = s_x[g][j1],          xB = s_x[g][j2];                     \
        const float aA = am1 * s_lx[g][j1],   aB = am1 * s_lx[g][j2];              \
        const int   iA = s_im[g][j1],         iB = s_im[g][j2];                    \
        int mm = (iA > iB) ? iA : iB;                                              \
        mm = max(mm, __shfl_xor(mm, 4, 64));   /* max over the wave's 16 groups */ \
        mm = max(mm, __shfl_xor(mm, 8, 64));                                       \
        mm = max(mm, __shfl_xor(mm, 16, 64));                                      \
        mm = max(mm, __shfl_xor(mm, 32, 64));                                      \
        const int M = __builtin_amdgcn_readfirstlane((mm + 3) >> 2);               \
        float aA0 = 0.f, aA1 = 0.f, aB0 = 0.f, aB1 = 0.f;                          \
        float2 t0 = P0, t1 = P1;                                                   \
        int m = 0;                                                                 \
        for (; m + 2 <= M; m += 2) {                                               \
            const float2 n0 = s_num[(m + 2) * 4 + sub + 1];                        \
            const float2 n1 = s_num[(m + 3) * 4 + sub + 1];                        \
            const int i0 = m * 4 + sub + 1;                                        \
            const int i1 = i0 + 4;                                                 \
            const float wA0 = fmaf(-t0.x, xA, 1.0f);                               \
            const float wA1 = fmaf(-t1.x, xA, 1.0f);                               \
            const float wB0 = fmaf(-t0.x, xB, 1.0f);                               \
            const float wB1 = fmaf(-t1.x, xB, 1.0f);                               \
            const float eA0 = fmaf(bm1, __log2f(wA0), fmaf(am1, t0.y, aA));        \
            const float eA1 = fmaf(bm1, __log2f(wA1), fmaf(am1, t1.y, aA));        \
            const float eB0 = fmaf(bm1, __log2f(wB0), fmaf(am1, t0.y, aB));        \
            const float eB1 = fmaf(bm1, __log2f(wB1), fmaf(am1, t1.y, aB));        \
            const float yA0 = exp2_fast(eA0), yA1 = exp2_fast(eA1);                \
            const float yB0 = exp2_fast(eB0), yB1 = exp2_fast(eB1);                \
            aA0 += (i0 <= iA) ? yA0 : 0.f;                                         \
            aA1 += (i1 <= iA) ? yA1 : 0.f;                                         \
            aB0 += (i0 <= iB) ? yB0 : 0.f;                                         \
            aB1 += (i1 <= iB) ? yB1 : 0.f;                                         \
            t0 = n0; t1 = n1;                                                      \
        }                                                                          \
        if (m < M) {                                                               \
            const int i0 = m * 4 + sub + 1;                                        \
            const float wA0 = fmaf(-t0.x, xA, 1.0f);                               \
            const float wB0 = fmaf(-t0.x, xB, 1.0f);                               \
            const float eA0 = fmaf(bm1, __log2f(wA0), fmaf(am1, t0.y, aA));        \
            const float eB0 = fmaf(bm1, __log2f(wB0), fmaf(am1, t0.y, aB));        \
            aA0 += (i0 <= iA) ? exp2_fast(eA0) : 0.f;                              \
            aB0 += (i0 <= iB) ? exp2_fast(eB0) : 0.f;                              \
        }                                                                          \
        acc[j1] = aA0 + aA1;                                                       \
        acc[j2] = aB0 + aB1;                                                       \
    }

    PAIR_LOOP(0, 1)
    PAIR_LOOP(2, 3)
    PAIR_LOOP(4, 5)
    PAIR_LOOP(6, 7)
#undef PAIR_LOOP

    // ---- edge 8 merged with denominator: fixed 16 chunks ----------------------
    // Den evals (1 per chunk per lane, m ascending 0..15, same expression) are
    // bit-identical to R11's separate 16-eval loop. Edge-8 chunks beyond its old
    // wave-max M are masked to exact +0.0 (x8 < 1 keeps w > 0: finite math).
    // No scalar M needed -> edge 8's shfl-max reduce removed entirely.
    {
        const float xj  = s_x[g][8];
        const float axj = am1 * s_lx[g][8];
        const int   imv = s_im[g][8];
        float a0 = 0.f, a1 = 0.f;
        float2 t0 = P0, t1 = P1;
        float2 d0 = s_den[sub], d1 = s_den[sub + 4];
#pragma unroll 4
        for (int m = 0; m + 2 <= 16; m += 2) {
            const float2 n0  = s_num[(m + 2) * 4 + sub + 1];
            const float2 n1  = s_num[(m + 3) * 4 + sub + 1];
            const float2 nd0 = s_den[(m + 2) * 4 + sub];
            const float2 nd1 = s_den[(m + 3) * 4 + sub];
            const int i0 = m * 4 + sub + 1;
            const int i1 = i0 + 4;
            const float w0 = fmaf(-t0.x, xj, 1.0f);
            const float w1 = fmaf(-t1.x, xj, 1.0f);
            const float e0v = fmaf(bm1, __log2f(w0), fmaf(am1, t0.y, axj));
            const float e1v = fmaf(bm1, __log2f(w1), fmaf(am1, t1.y, axj));
            const float y0 = exp2_fast(e0v);
            const float y1 = exp2_fast(e1v);
            a0 += (i0 <= imv) ? y0 : 0.f;
            a1 += (i1 <= imv) ? y1 : 0.f;
            accD += exp2_fast(fmaf(bm1, d0.y, am1 * d0.x));
            accD += exp2_fast(fmaf(bm1, d1.y, am1 * d1.x));
            t0 = n0; t1 = n1; d0 = nd0; d1 = nd1;
        }
        acc[8] = a0 + a1;
    }

    // ---- reduce across the 4-group --------------------------------------------
#pragma unroll
    for (int d = 1; d < 4; d <<= 1) {
        accD += __shfl_xor(accD, d, 64);
#pragma unroll
        for (int j = 0; j < 9; ++j) acc[j] += __shfl_xor(acc[j], d, 64);
    }

    // ---- epilogue: cdf -> mass; lane sub stores indices {sub, sub+4, sub+8} ---
    const float dtf = (float)(1.0 / 63.0);
    const float rB  = 1.0f / (accD * dtf);
    float cdfv[9];
#pragma unroll
    for (int j = 0; j < 9; ++j) cdfv[j] = (acc[j] * dtf) * rB;

    const float o0 = (sub == 0) ? cdfv[0]
                   : (sub == 1) ? (cdfv[1] - cdfv[0])
                   : (sub == 2) ? (cdfv[2] - cdfv[1])
                   :              (cdfv[3] - cdfv[2]);
    const float o1 = (sub == 0) ? (cdfv[4] - cdfv[3])
                   : (sub == 1) ? (cdfv[5] - cdfv[4])
                   : (sub == 2) ? (cdfv[6] - cdfv[5])
                   :              (cdfv[7] - cdfv[6]);
    const float o2 = (sub == 0) ? (cdfv[8] - cdfv[7])
                   :              (1.0f - cdfv[8]);   // sub==1; sub>=2 unused
    if (valid) {
        const long long ob = (long long)s * 10;
        out[ob + sub]     = o0;
        out[ob + 4 + sub] = o1;
        if (sub < 2) out[ob + 8 + sub] = o2;
    }
}

extern "C" void kernel_launch(void* const* d_in, const int* in_sizes, int n_in,
                              void* d_out, int out_size, void* d_ws, size_t ws_size,
                              hipStream_t stream) {
    (void)n_in; (void)out_size; (void)d_ws; (void)ws_size;
    const int*   uid = (const int*)d_in[0];
    const int*   iid = (const int*)d_in[1];
    const float* uf  = (const float*)d_in[2];
    const float* vf  = (const float*)d_in[3];
    const float* ubt = (const float*)d_in[4];
    const float* ibt = (const float*)d_in[5];
    const float* uae = (const float*)d_in[6];
    const float* ube = (const float*)d_in[7];
    const float* iae = (const float*)d_in[8];
    const float* ibe = (const float*)d_in[9];
    const float* gb  = (const float*)d_in[10];
    float* out = (float*)d_out;
    const int B = in_sizes[0];
    const int grid = (B + SPB - 1) / SPB;
    hipLaunchKernelGGL(lbd_kernel, dim3(grid), dim3(BLOCK), 0, stream,
                       uid, iid, uf, vf, ubt, ibt, uae, ube, iae, ibe, gb, out, B);
}

// Round 2
// 121.923 us; speedup vs baseline: 1.0197x; 1.0069x over previous
//
#include <hip/hip_runtime.h>
#include <math.h>

#define BLOCK 256
#define SPB (BLOCK / 4)   // 64 samples per block; 4 lanes cooperate per sample
// Session rules: (R4) no runtime-indexed register arrays; (R5) no fine-grained
// scalar guards around register-resident straight-line code; (R9) exact-count
// pairing + i=1 shift; (R11) merged adjacent edge pairs; (R12) LDS record
// handoff (neutral but kept: cheap, decouples phases).
// R13 (this rev): latency restructure, bit-identical math.
//  - t-table lives in registers (float2 tc[16]); ALL hot loops fully unrolled
//    with compile-time indices + wave-uniform scalar early-exit -> zero LDS
//    reads / lgkm waits on any loop-carried dependency chain.
//  - all four pair-wise wave-max shfl chains hoisted and interleaved (latency
//    overlaps instead of serializing 4x before each loop).
//  - edge-8/den loop fully unrolled; s_den reads at static addresses.
//  - __launch_bounds__(BLOCK,4) pins the <=128-VGPR / 4-wave bracket.

struct F4a4 { float a, b, c, d; };   // 16B load at 4B alignment -> global_load_dwordx4

__device__ __forceinline__ float exp2_fast(float x) {
#if __has_builtin(__builtin_amdgcn_exp2f)
    return __builtin_amdgcn_exp2f(x);   // bare v_exp_f32
#else
    return __expf(x * 0.69314718055994531f);
#endif
}

// Inline f64 exp, rel err ~7e-15. Proven R5-R10 (absmax identical to libm).
__device__ __forceinline__ double exp_f64_fast(double x) {
    const double L2E = 1.4426950408889634074;
    const double LN2 = 0.69314718055994530942;
    double n = rint(x * L2E);
    double r = fma(x, L2E, -n);
    double w = r * LN2;
    double p = 2.08767569878680989792e-9;             // 1/12!
    p = fma(p, w, 2.50521083854417187751e-8);
    p = fma(p, w, 2.75573192239858906526e-7);
    p = fma(p, w, 2.75573192239858925110e-6);
    p = fma(p, w, 2.48015873015873015873e-5);
    p = fma(p, w, 1.98412698412698412698e-4);
    p = fma(p, w, 1.38888888888888888889e-3);
    p = fma(p, w, 8.33333333333333333333e-3);
    p = fma(p, w, 4.16666666666666666667e-2);
    p = fma(p, w, 1.66666666666666666667e-1);
    p = fma(p, w, 0.5);
    p = fma(p, w, 1.0);
    p = fma(p, w, 1.0);
    const double sc = __longlong_as_double((long long)(1023 + (int)n) << 52);
    return p * sc;
}

__global__ __launch_bounds__(BLOCK, 4) void lbd_kernel(
    const int* __restrict__ uid_in, const int* __restrict__ iid_in,
    const float* __restrict__ uf,  const float* __restrict__ vf,
    const float* __restrict__ ubt, const float* __restrict__ ibt,
    const float* __restrict__ uae, const float* __restrict__ ube,
    const float* __restrict__ iae, const float* __restrict__ ibe,
    const float* __restrict__ gbp, float* __restrict__ out, int B)
{
    // Sample-independent t-grid tables: built once per block.
    // s_num[64..] pad entries are (t=1, lt=0) -> finite math, masked to exact 0.
    __shared__ float2 s_num[76];       // (t_i, log2 t_i)
    __shared__ float2 s_den[72];       // (log2 t_i, log2(1-t_i)); [63] -> -inf => exact 0
    // Per-sample edge records (phase-1 -> phase-2 handoff). Row stride 10:
    // coprime with 32 banks -> conflict-free broadcast reads across groups.
    __shared__ float  s_x [SPB][10];
    __shared__ float  s_lx[SPB][10];
    __shared__ int    s_im[SPB][10];

    const int tid = threadIdx.x;
    {
        const double STEP0 = 1.0 / 63.0;
        if (tid < 76) {
            const float tf = (tid >= 63) ? 1.0f : (float)((double)tid * STEP0); // exact np linspace f32
            s_num[tid] = make_float2(tf, __log2f(tf));      // tid>=63 -> (1, 0)
        }
        if (tid < 72) {
            float l1 = 0.f, l2 = 0.f;
            if (tid < 64) {
                const float tf = (tid >= 63) ? 1.0f : (float)((double)tid * STEP0);
                l1 = __log2f(tf);
                l2 = __log2f(1.0f - tf);                    // tid==63 -> -inf
            }
            s_den[tid] = make_float2(l1, l2);
        }
    }
    __syncthreads();

    const int sub = tid & 3;                          // lane within 4-lane sample group
    const int g   = tid >> 2;                         // sample group within block
    const int s0  = blockIdx.x * SPB + g;
    const bool valid = (s0 < B);
    const int s = valid ? s0 : (B - 1);               // clamp: keep lanes live for shuffles

    const int u = uid_in[s];
    const int v = iid_in[s];

    // ---- feature gather: 4 x dwordx4 per table; lane covers 16c+4*sub..+3 -----
    const float* pu = uf + (long long)u * 65;
    const float* pv = vf + (long long)v * 65;
    float dotp = 0.f, sup = 0.f, svp = 0.f;
#pragma unroll
    for (int c = 0; c < 4; ++c) {
        const F4a4 a = *(const F4a4*)(pu + c * 16 + sub * 4);
        const F4a4 b = *(const F4a4*)(pv + c * 16 + sub * 4);
        dotp += a.a * b.a + a.b * b.b + a.c * b.c + a.d * b.d;
        sup  += a.a * a.a + a.b * a.b + a.c * a.c + a.d * a.d;
        svp  += b.a * b.a + b.b * b.b + b.c * b.c + b.d * b.d;
    }
#pragma unroll
    for (int d = 1; d < 4; d <<= 1) {                 // butterfly within 4-group
        dotp += __shfl_xor(dotp, d, 64);
        sup  += __shfl_xor(sup,  d, 64);
        svp  += __shfl_xor(svp,  d, 64);
    }

    // ---- embedding gather dedup: 1 load/lane + shuffles (smooth path) ---------
    float emb;
    {
        const float* ep = (sub == 0) ? (uae + u)
                        : (sub == 1) ? (iae + v)
                        : (sub == 2) ? (ube + u)
                        :              (ibe + v);
        emb = *ep;
    }
    const float ua_ = __shfl(emb, 0, 4);
    const float ia_ = __shfl(emb, 1, 4);
    const float ub_ = __shfl(emb, 2, 4);
    const float ib_ = __shfl(emb, 3, 4);

    // ---- alpha / beta (smooth; 4 lanes redundantly) ---------------------------
    const float gb = gbp[0];
    const float len_prod = sqrtf(sup) * sqrtf(svp);
    const float EPS = 1e-6f;
    const float HI  = (float)(1.0 - 1e-6);
    float mu = 0.5f + (0.5f * dotp) / fmaxf(len_prod, EPS);
    mu = fminf(fmaxf(mu, EPS), HI);
    const float ups = fmaxf(fabsf(dotp), EPS);
    const float al0 = fmaxf(0.01f, mu * ups);
    const float be0 = fmaxf(0.01f, ups - al0);
    const float alpha = fmaxf(0.01f, ((gb + al0) + ua_) + ia_);
    const float beta  = fmaxf(0.01f, ((gb + be0) + ub_) + ib_);
    const float am1 = alpha - 1.0f;                   // > 0 (gb = 2.0)
    const float bm1 = beta  - 1.0f;                   // > 0

    // ---- bin-edge chain in f64 (mask-critical; slop budget ~1e-11 rel) --------
    // Lane sub owns contiguous bins lb..lb+2 (lane3: bin 9 only).
    const double STEP = 1.0 / 63.0;
    const int lb = 3 * sub;
    double e0, e1 = 0.0, e2 = 0.0;
    {
        const long long ur = (long long)u * 10, vr = (long long)v * 10;
        const int i1 = (lb + 1 <= 9) ? lb + 1 : 9;    // clamp to stay in-bounds
        const int i2 = (lb + 2 <= 9) ? lb + 2 : 9;
        e0 = exp_f64_fast((double)ubt[ur + lb] + (double)ibt[vr + lb]);
        const double t1 = exp_f64_fast((double)ubt[ur + i1] + (double)ibt[vr + i1]);
        const double t2 = exp_f64_fast((double)ubt[ur + i2] + (double)ibt[vr + i2]);
        if (lb + 1 <= 9) e1 = t1;                     // lane3 contributes only bin 9
        if (lb + 2 <= 9) e2 = t2;
    }
    const double c0 = e0, c1 = c0 + e1, c2 = c1 + e2; // local cumsum (3 bins)
    double p = c2;                                    // local total
#pragma unroll
    for (int d = 1; d < 4; d <<= 1) {                 // inclusive scan of totals
        const double t = __shfl_up(p, d, 4);
        if (sub >= d) p += t;
    }
    const double ssum = __shfl(p, 3, 4);              // grand total (10 bins)
    const double rsum = 1.0 / ssum;                   // 1 IEEE div; <=2ulp slop ok
    const double ex   = p - c2;                       // exclusive prefix
    // own edges -> LDS record (global edge index lb+r, valid if <= 8)
    const double cg0 = ex + c0, cg1 = ex + c1, cg2 = ex + c2;
#pragma unroll
    for (int r = 0; r < 3; ++r) {
        const double cgr = (r == 0) ? cg0 : (r == 1) ? cg1 : cg2;
        if (lb + r <= 8) {
            const double x = cgr * rsum;              // f64 mul by reciprocal
            int k = (int)(x * 63.0);
            k = (k > 62) ? 62 : k;
            const int dec = ((double)k * STEP > x) ? 1 : 0;
            const int inc = ((k < 62) && ((double)(k + 1) * STEP <= x)) ? 1 : 0;
            const float xf = (float)x;
            s_im[g][lb + r] = k + inc - dec;          // exact im, branch-free
            s_x [g][lb + r] = xf;
            s_lx[g][lb + r] = __log2f(xf);
        }
    }
    __syncthreads();   // record visibility

    // ---- register t-table: chunk c covers quad index i = 4c+sub+1 -------------
    // tc[15] reaches i=64 for sub==3: the (1,0) pad entry, always masked to 0
    // (im <= 62). All indices below are compile-time (R4-safe).
    float2 tc[16];
#pragma unroll
    for (int c = 0; c < 16; ++c) tc[c] = s_num[c * 4 + sub + 1];

    // ---- per-edge im records + interleaved pair-max chains --------------------
    // max(ceil(iA/4), ceil(iB/4)) == ceil(max(iA,iB)/4): M identical to R11/R12.
    // Four independent shfl chains issued together -> DS latency overlaps.
    int imr[9];
#pragma unroll
    for (int j = 0; j < 9; ++j) imr[j] = s_im[g][j];
    int p01 = (imr[0] > imr[1]) ? imr[0] : imr[1];
    int p23 = (imr[2] > imr[3]) ? imr[2] : imr[3];
    int p45 = (imr[4] > imr[5]) ? imr[4] : imr[5];
    int p67 = (imr[6] > imr[7]) ? imr[6] : imr[7];
#pragma unroll
    for (int d = 4; d <= 32; d <<= 1) {               // max over the wave's 16 groups
        p01 = max(p01, __shfl_xor(p01, d, 64));
        p23 = max(p23, __shfl_xor(p23, d, 64));
        p45 = max(p45, __shfl_xor(p45, d, 64));
        p67 = max(p67, __shfl_xor(p67, d, 64));
    }
    const int M01 = __builtin_amdgcn_readfirstlane((p01 + 3) >> 2);   // scalar chunks 0..16
    const int M23 = __builtin_amdgcn_readfirstlane((p23 + 3) >> 2);
    const int M45 = __builtin_amdgcn_readfirstlane((p45 + 3) >> 2);
    const int M67 = __builtin_amdgcn_readfirstlane((p67 + 3) >> 2);

    float acc[9];
    float accD = 0.f;

    // ---- fully-unrolled guarded steps: chunks m (->a?0) and m+1 (->a?1) -------
    // Same guarded accumulation order as the R11/R12 rolling loops (dual steps
    // while m+2<=M, then one single step if m<M) -> bit-identical per-edge sums.
#define DUAL(m)                                                                    \
    if ((m) + 2 <= M) {                                                            \
        const float2 t0 = tc[(m)], t1 = tc[(m) + 1];                               \
        const int i0 = (m) * 4 + sub + 1;                                          \
        const int i1 = (m) * 4 + sub + 5;                                          \
        const float wA0 = fmaf(-t0.x, xA, 1.0f);                                   \
        const float wA1 = fmaf(-t1.x, xA, 1.0f);                                   \
        const float wB0 = fmaf(-t0.x, xB, 1.0f);                                   \
        const float wB1 = fmaf(-t1.x, xB, 1.0f);                                   \
        const float eA0 = fmaf(bm1, __log2f(wA0), fmaf(am1, t0.y, aA));            \
        const float eA1 = fmaf(bm1, __log2f(wA1), fmaf(am1, t1.y, aA));            \
        const float eB0 = fmaf(bm1, __log2f(wB0), fmaf(am1, t0.y, aB));            \
        const float eB1 = fmaf(bm1, __log2f(wB1), fmaf(am1, t1.y, aB));            \
        const float yA0 = exp2_fast(eA0), yA1 = exp2_fast(eA1);                    \
        const float yB0 = exp2_fast(eB0), yB1 = exp2_fast(eB1);                    \
        aA0 += (i0 <= iA) ? yA0 : 0.f;                                             \
        aA1 += (i1 <= iA) ? yA1 : 0.f;                                             \
        aB0 += (i0 <= iB) ? yB0 : 0.f;                                             \
        aB1 += (i1 <= iB) ? yB1 : 0.f;                                             \
    } else {                                                                       \
        if ((m) < M) {                                                             \
            const float2 t0 = tc[(m)];                                             \
            const int i0 = (m) * 4 + sub + 1;                                      \
            const float wA0 = fmaf(-t0.x, xA, 1.0f);                               \
            const float wB0 = fmaf(-t0.x, xB, 1.0f);                               \
            const float eA0 = fmaf(bm1, __log2f(wA0), fmaf(am1, t0.y, aA));        \
            const float eB0 = fmaf(bm1, __log2f(wB0), fmaf(am1, t0.y, aB));        \
            aA0 += (i0 <= iA) ? exp2_fast(eA0) : 0.f;                              \
            aB0 += (i0 <= iB) ? exp2_fast(eB0) : 0.f;                              \
        }                                                                          \
        break;                                                                     \
    }

#define PAIR_LOOP(j1, j2, Mv)                                                      \
    {                                                                              \
        const float xA = s_x[g][j1],        xB = s_x[g][j2];                       \
        const float aA = am1 * s_lx[g][j1], aB = am1 * s_lx[g][j2];                \
        const int   iA = imr[j1],           iB = imr[j2];                          \
        const int   M  = Mv;                                                       \
        float aA0 = 0.f, aA1 = 0.f, aB0 = 0.f, aB1 = 0.f;                          \
        do {                                                                       \
            DUAL(0) DUAL(2) DUAL(4) DUAL(6) DUAL(8) DUAL(10) DUAL(12) DUAL(14)    \
        } while (0);                                                               \
        acc[j1] = aA0 + aA1;                                                       \
        acc[j2] = aB0 + aB1;                                                       \
    }

    PAIR_LOOP(0, 1, M01)
    PAIR_LOOP(2, 3, M23)
    PAIR_LOOP(4, 5, M45)
    PAIR_LOOP(6, 7, M67)
#undef PAIR_LOOP
#undef DUAL

    // ---- edge 8 merged with denominator: fixed 16 chunks, fully unrolled ------
    // Den evals ascend m (2 per dual chunk), same expressions/order as R12 ->
    // bit-identical. Edge-8 chunks beyond its wave max are masked to exact +0.0.
    {
        const float xj  = s_x[g][8];
        const float axj = am1 * s_lx[g][8];
        const int   imv = imr[8];
        float a0 = 0.f, a1 = 0.f;
#pragma unroll
        for (int m = 0; m < 16; m += 2) {
            const float2 t0 = tc[m], t1 = tc[m + 1];
            const float2 d0 = s_den[m * 4 + sub];
            const float2 d1 = s_den[(m + 1) * 4 + sub];
            const int i0 = m * 4 + sub + 1;
            const int i1 = i0 + 4;
            const float w0 = fmaf(-t0.x, xj, 1.0f);
            const float w1 = fmaf(-t1.x, xj, 1.0f);
            const float e0v = fmaf(bm1, __log2f(w0), fmaf(am1, t0.y, axj));
            const float e1v = fmaf(bm1, __log2f(w1), fmaf(am1, t1.y, axj));
            const float y0 = exp2_fast(e0v);
            const float y1 = exp2_fast(e1v);
            a0 += (i0 <= imv) ? y0 : 0.f;
            a1 += (i1 <= imv) ? y1 : 0.f;
            accD += exp2_fast(fmaf(bm1, d0.y, am1 * d0.x));
            accD += exp2_fast(fmaf(bm1, d1.y, am1 * d1.x));
        }
        acc[8] = a0 + a1;
    }

    // ---- reduce across the 4-group --------------------------------------------
#pragma unroll
    for (int d = 1; d < 4; d <<= 1) {
        accD += __shfl_xor(accD, d, 64);
#pragma unroll
        for (int j = 0; j < 9; ++j) acc[j] += __shfl_xor(acc[j], d, 64);
    }

    // ---- epilogue: cdf -> mass; lane sub stores indices {sub, sub+4, sub+8} ---
    const float dtf = (float)(1.0 / 63.0);
    const float rB  = 1.0f / (accD * dtf);
    float cdfv[9];
#pragma unroll
    for (int j = 0; j < 9; ++j) cdfv[j] = (acc[j] * dtf) * rB;

    const float o0 = (sub == 0) ? cdfv[0]
                   : (sub == 1) ? (cdfv[1] - cdfv[0])
                   : (sub == 2) ? (cdfv[2] - cdfv[1])
                   :              (cdfv[3] - cdfv[2]);
    const float o1 = (sub == 0) ? (cdfv[4] - cdfv[3])
                   : (sub == 1) ? (cdfv[5] - cdfv[4])
                   : (sub == 2) ? (cdfv[6] - cdfv[5])
                   :              (cdfv[7] - cdfv[6]);
    const float o2 = (sub == 0) ? (cdfv[8] - cdfv[7])
                   :              (1.0f - cdfv[8]);   // sub==1; sub>=2 unused
    if (valid) {
        const long long ob = (long long)s * 10;
        out[ob + sub]     = o0;
        out[ob + 4 + sub] = o1;
        if (sub < 2) out[ob + 8 + sub] = o2;
    }
}

extern "C" void kernel_launch(void* const* d_in, const int* in_sizes, int n_in,
                              void* d_out, int out_size, void* d_ws, size_t ws_size,
                              hipStream_t stream) {
    (void)n_in; (void)out_size; (void)d_ws; (void)ws_size;
    const int*   uid = (const int*)d_in[0];
    const int*   iid = (const int*)d_in[1];
    const float* uf  = (const float*)d_in[2];
    const float* vf  = (const float*)d_in[3];
    const float* ubt = (const float*)d_in[4];
    const float* ibt = (const float*)d_in[5];
    const float* uae = (const float*)d_in[6];
    const float* ube = (const float*)d_in[7];
    const float* iae = (const float*)d_in[8];
    const float* ibe = (const float*)d_in[9];
    const float* gb  = (const float*)d_in[10];
    float* out = (float*)d_out;
    const int B = in_sizes[0];
    const int grid = (B + SPB - 1) / SPB;
    hipLaunchKernelGGL(lbd_kernel, dim3(grid), dim3(BLOCK), 0, stream,
                       uid, iid, uf, vf, ubt, ibt, uae, ube, iae, ibe, gb, out, B);
}